// Round 8
// baseline (183.151 us; speedup 1.0000x reference)
//
#include <hip/hip_runtime.h>
#include <stdint.h>

#define TSEQ 2048
#define NHEAD 16

typedef __attribute__((ext_vector_type(8))) short bf16x8;
typedef __attribute__((ext_vector_type(4))) short bf16x4;
typedef __attribute__((ext_vector_type(4))) float f32x4;

__device__ __forceinline__ unsigned short f2bf(float f) {
  union { float f; uint32_t u; } c;
  c.f = f;
  uint32_t u = c.u;
  u += 0x7fffu + ((u >> 16) & 1u);   // round-nearest-even
  return (unsigned short)(u >> 16);
}

__device__ __forceinline__ float fexp2(float x) {
#if __has_builtin(__builtin_amdgcn_exp2f)
  return __builtin_amdgcn_exp2f(x);
#else
  return __builtin_exp2f(x);
#endif
}

using as3_void  = __attribute__((address_space(3))) void;
using as1_cvoid = const __attribute__((address_space(1))) void;

__device__ __forceinline__ void gld_lds16(const void* g, void* l) {
  // async global->LDS, 16B/lane; LDS dest = wave-uniform base + lane*16
  __builtin_amdgcn_global_load_lds((as1_cvoid*)g, (as3_void*)l, 16, 0, 0);
}

#define LGKM0() do { asm volatile("s_waitcnt lgkmcnt(0)" ::: "memory"); \
                     __builtin_amdgcn_sched_barrier(0); } while (0)

// ---------------- prep kernels (produce K-swizzled global layouts) ----------------
// GEMM operand layout: X'[row][k] = X[row][k ^ ((row&7)<<3)] within each 64-elem k-block.

__global__ void cast_x_kernel(const float4* __restrict__ x, unsigned short* __restrict__ xb) {
  int i = blockIdx.x * 256 + threadIdx.x;   // group of 4 elems
  float4 v = x[i];
  int e = i * 4;
  int m = e >> 10, k = e & 1023;
  int ks = k ^ ((m & 7) << 3);
  ushort4 o;
  o.x = f2bf(v.x); o.y = f2bf(v.y); o.z = f2bf(v.z); o.w = f2bf(v.w);
  *(ushort4*)(xb + (size_t)m * 1024 + ks) = o;
}

// Wq/Wk/Wv [H,C,HD] f32 -> BT[(which*1024 + h*64 + d)][c ^ swz(d)] bf16
__global__ void repack_wqkv(const float* __restrict__ Wq, const float* __restrict__ Wk,
                            const float* __restrict__ Wv, unsigned short* __restrict__ BT) {
  __shared__ unsigned short tile[64][72];
  const float* W = (blockIdx.z == 0) ? Wq : (blockIdx.z == 1) ? Wk : Wv;
  const int h = blockIdx.y;
  const int c0 = blockIdx.x * 64;
  const int t = threadIdx.x;
  const float* src = W + ((size_t)h * 1024 + c0) * 64;
#pragma unroll
  for (int p = 0; p < 16; ++p) {
    int idx = p * 256 + t;
    int cc = idx >> 6, d = idx & 63;
    tile[cc][d] = f2bf(src[(size_t)cc * 64 + d]);
  }
  __syncthreads();
  unsigned short* dst = BT + ((size_t)blockIdx.z * 1024 + (size_t)h * 64) * 1024 + c0;
#pragma unroll
  for (int p = 0; p < 16; ++p) {
    int idx = p * 256 + t;
    int d = idx >> 6, cc = idx & 63;
    dst[(size_t)d * 1024 + (cc ^ ((d & 7) << 3))] = tile[cc][d];
  }
}

// Wo [C,C] f32 -> WoT[n][k ^ swz(n)] bf16 (transpose + swizzle)
__global__ void repack_wo(const float* __restrict__ Wo, unsigned short* __restrict__ WoT) {
  __shared__ unsigned short tile[64][72];
  const int k0 = blockIdx.x * 64;
  const int n0 = blockIdx.y * 64;
  const int t = threadIdx.x;
#pragma unroll
  for (int p = 0; p < 16; ++p) {
    int idx = p * 256 + t;
    int kk = idx >> 6, nn = idx & 63;
    tile[kk][nn] = f2bf(Wo[(size_t)(k0 + kk) * 1024 + n0 + nn]);
  }
  __syncthreads();
#pragma unroll
  for (int p = 0; p < 16; ++p) {
    int idx = p * 256 + t;
    int nn = idx >> 6, kk = idx & 63;
    WoT[(size_t)(n0 + nn) * 1024 + k0 + (kk ^ ((nn & 7) << 3))] = tile[kk][nn];
  }
}

// ---------------- QKV GEMM: 256x256, 8-wave, 4-phase/K-tile, counted vmcnt ----------
// C[8192,3072] = A * BT^T + bias.  8 waves = 2M x 4N; interleaved frags:
//   M-frag ii at row wr*16 + ii*32 (ii 0..7)  -> m-half0 = A-h0 rows, ∀ waves
//   N-frag jj at col wc*16 + jj*64 (jj 0..3)  -> n-half maps to B half-tiles
// LDS: bufq A at q*32K, B at 64K + q*32K; half-tile = 16KB = 2 gld_lds/thread.
// Per K-tile j (buf q=j&1), phases ph0..ph3 = (m0,n0)(m0,n1)(m1,n0)(m1,n1);
// stages: ph0: Bh1(j+1)  ph1: Ah1(j+1) [other buf]  ph2: Ah0(j+2)  ph3: Bh0(j+2) [this buf,
// regions freed at ph1/ph2 resp.].  vmcnt(4) once per K-tile (retires through Ah1(j+1));
// vmcnt(0) at j>=NT-2 (tail).  Raw s_barrier; lgkmcnt(0)+sched_barrier; setprio MFMA.

__global__ __launch_bounds__(512, 2) void gemm256(
    const unsigned short* __restrict__ A, const unsigned short* __restrict__ BTm,
    const float* __restrict__ bias0, const float* __restrict__ bias1,
    const float* __restrict__ bias2,
    unsigned short* __restrict__ qo, unsigned short* __restrict__ ko,
    unsigned short* __restrict__ vto) {
  __shared__ __align__(16) char lds[131072];
  constexpr int K = 1024, NT = 16;

  const int tid = threadIdx.x, lane = tid & 63, w = tid >> 6;
  const int wr = w >> 2, wc = w & 3;
  const int g = lane >> 4, r = lane & 15;
  const int bid = blockIdx.x;
  const int bid2 = (bid & 7) * 48 + (bid >> 3);   // XCD-chunked (384 % 8 == 0)
  const int bx = bid2 / 12, by = bid2 % 12;
  const int m0 = bx * 256, n0 = by * 256;
  const int xr = (r & 7) << 4;

  const unsigned short* Ag = A + (size_t)m0 * K;
  const unsigned short* Bg = BTm + (size_t)n0 * K;

  f32x4 acc[8][4] = {};
  bf16x8 a_[4][2], b_[2][2];

#define STAGEH(op, hh, tt) do {                                                   \
    const unsigned short* gp_ = (op) ? Bg : Ag;                                   \
    char* lp_ = lds + (op) * 65536 + ((tt) & 1) * 32768 + (hh) * 16384 + w * 1024;\
    gld_lds16(gp_ + (size_t)((hh) * 128 + (tid >> 3)) * K + (tt) * 64 + (tid & 7) * 8, lp_);          \
    gld_lds16(gp_ + (size_t)((hh) * 128 + 64 + (tid >> 3)) * K + (tt) * 64 + (tid & 7) * 8, lp_ + 8192); \
  } while (0)

#define RDA(mp, q_) do { _Pragma("unroll") for (int ii = 0; ii < 4; ++ii) {       \
    const char* p_ = lds + (q_) * 32768 + (wr * 16 + ((mp) * 4 + ii) * 32 + r) * 128; \
    a_[ii][0] = *(const bf16x8*)(p_ + ((g * 16) ^ xr));                           \
    a_[ii][1] = *(const bf16x8*)(p_ + ((64 + g * 16) ^ xr)); } } while (0)

#define RDB(np, q_) do { _Pragma("unroll") for (int jj = 0; jj < 2; ++jj) {       \
    const char* p_ = lds + 65536 + (q_) * 32768 + (wc * 16 + ((np) * 2 + jj) * 64 + r) * 128; \
    b_[jj][0] = *(const bf16x8*)(p_ + ((g * 16) ^ xr));                           \
    b_[jj][1] = *(const bf16x8*)(p_ + ((64 + g * 16) ^ xr)); } } while (0)

#define MFMA16(mp, np) do {                                                       \
    __builtin_amdgcn_s_setprio(1);                                                \
    _Pragma("unroll") for (int ii = 0; ii < 4; ++ii)                              \
    _Pragma("unroll") for (int jj = 0; jj < 2; ++jj) {                            \
      f32x4& ac_ = acc[(mp) * 4 + ii][(np) * 2 + jj];                             \
      ac_ = __builtin_amdgcn_mfma_f32_16x16x32_bf16(a_[ii][0], b_[jj][0], ac_, 0, 0, 0); \
      ac_ = __builtin_amdgcn_mfma_f32_16x16x32_bf16(a_[ii][1], b_[jj][1], ac_, 0, 0, 0); \
    }                                                                             \
    __builtin_amdgcn_s_setprio(0);                                                \
  } while (0)

  // prologue: tile0 fully + tile1 first halves; retire tile0, keep 2 halves in flight
  STAGEH(0, 0, 0); STAGEH(1, 0, 0); STAGEH(1, 1, 0); STAGEH(0, 1, 0);
  STAGEH(0, 0, 1); STAGEH(1, 0, 1);
  asm volatile("s_waitcnt vmcnt(4)" ::: "memory");
  __builtin_amdgcn_s_barrier();

  for (int j = 0; j < NT; ++j) {
    const int q = j & 1;
    // ---- ph0 (m0,n0) ----
    RDA(0, q); RDB(0, q);
    if (j + 1 < NT) STAGEH(1, 1, j + 1);
    __builtin_amdgcn_s_barrier();
    LGKM0();
    MFMA16(0, 0);
    __builtin_amdgcn_s_barrier();
    // ---- ph1 (m0,n1) ----
    RDB(1, q);
    if (j + 1 < NT) STAGEH(0, 1, j + 1);
    __builtin_amdgcn_s_barrier();
    LGKM0();
    MFMA16(0, 1);
    __builtin_amdgcn_s_barrier();
    // ---- ph2 (m1,n0) ----
    RDA(1, q); RDB(0, q);
    if (j + 2 < NT) STAGEH(0, 0, j + 2);
    __builtin_amdgcn_s_barrier();
    LGKM0();
    MFMA16(1, 0);
    __builtin_amdgcn_s_barrier();
    // ---- ph3 (m1,n1) ----
    RDB(1, q);
    if (j + 2 < NT) STAGEH(1, 0, j + 2);
    __builtin_amdgcn_s_barrier();
    LGKM0();
    MFMA16(1, 1);
    if (j >= NT - 2) { asm volatile("s_waitcnt vmcnt(0)" ::: "memory"); }
    else             { asm volatile("s_waitcnt vmcnt(4)" ::: "memory"); }
    __builtin_amdgcn_s_barrier();
  }
#undef STAGEH
#undef RDA
#undef RDB
#undef MFMA16

  // ---------------- LDS-bounce epilogue (4 head-halves) ----------------
  const int which = n0 >> 10;  // 0=q 1=k 2=v (256 | 1024 -> uniform per block)
  const float* bias = (which == 0) ? bias0 : (which == 1) ? bias1 : bias2;
  const float sc = (which == 0) ? 0.18033688011112042f : 1.0f;  // 0.125*log2(e)
  const int b = m0 >> 11;
  const int t0 = m0 & 2047;
  const int hb0 = (n0 & 1023) >> 6;
  unsigned short* ep = (unsigned short*)lds;

  for (int h = 0; h < 4; ++h) {
    const int head = hb0 + h;
    const size_t bhb = (size_t)(b * NHEAD + head) * 131072;
    const float bvl = bias[head * 64 + wc * 16 + r];
    __syncthreads();
    if (which == 2) {
      // transposed tile ep[d][t], pitch 264 elems
#pragma unroll
      for (int ii = 0; ii < 8; ++ii)
#pragma unroll
        for (int j = 0; j < 4; ++j) {
          const int tin = wr * 16 + ii * 32 + 4 * g + j;
          ep[(wc * 16 + r) * 264 + tin] = f2bf(acc[ii][h][j] + bvl);
        }
    } else {
      // ep[t][d], pitch 72 elems
#pragma unroll
      for (int ii = 0; ii < 8; ++ii)
#pragma unroll
        for (int j = 0; j < 4; ++j) {
          const int tin = wr * 16 + ii * 32 + 4 * g + j;
          ep[tin * 72 + wc * 16 + r] = f2bf((acc[ii][h][j] + bvl) * sc);
        }
    }
    __syncthreads();
    if (which == 2) {
      // permuted+swizzled V^T store: slot qd holds t = (qd&4)*4 + ((qd>>3)&3)*4 + (qd&3)
#pragma unroll
      for (int p = 0; p < 4; ++p) {
        const int idx = p * 512 + tid;
        const int d = idx >> 5, rem = idx & 31;
        const int c = rem >> 3, wq = rem & 7;
        const int kk2 = wq >> 2, gg = wq & 3;
        const int base_t = c * 64 + kk2 * 32 + gg * 4;
        union { bf16x4 h4[2]; bf16x8 v8; } cc2;
        cc2.h4[0] = *(const bf16x4*)(ep + d * 264 + base_t);
        cc2.h4[1] = *(const bf16x4*)(ep + d * 264 + base_t + 16);
        *(bf16x8*)(vto + bhb + (size_t)((t0 >> 6) + c) * 4096 + (size_t)d * 64 +
                   ((wq * 8) ^ ((d & 7) << 3))) = cc2.v8;
      }
    } else {
      unsigned short* qk = (which == 1) ? ko : qo;
#pragma unroll
      for (int p = 0; p < 4; ++p) {
        const int row = p * 64 + (tid >> 3);
        const int seg = tid & 7;
        const bf16x8 v8 = *(const bf16x8*)(ep + row * 72 + seg * 8);
        const int tt = t0 + row;
        int dbase = seg * 8;
        if (which == 1) dbase ^= (tt & 7) << 3;
        *(bf16x8*)(qk + bhb + (size_t)tt * 64 + dbase) = v8;
      }
    }
  }
}

// ---------------- O-proj GEMM: 128x128 dbuf (proven R7 structure) ----------------

__global__ __launch_bounds__(256) void gemm_oproj(
    const unsigned short* __restrict__ A, const unsigned short* __restrict__ BTm,
    const float* __restrict__ bias0, float* __restrict__ outf, int K, int N) {
  __shared__ __align__(16) char lds[65536];   // 2 buf x (A 16K + B 16K)

  const int tid = threadIdx.x, lane = tid & 63, wv = tid >> 6;
  const int wr = wv >> 1, wc = wv & 1;
  const int g = lane >> 4, r = lane & 15;
  const int m0 = blockIdx.x * 128, n0 = blockIdx.y * 128;
  const int xr = (r & 7) << 4;

  f32x4 acc[4][4] = {};

  const int arow = tid >> 3;
  const int acol = (tid & 7) * 8;
  const unsigned short* Ab = A + (size_t)(m0 + arow) * K + acol;
  const unsigned short* Bb = BTm + (size_t)(n0 + arow) * K + acol;

#define GSTAGE(b, kel) do {                                                 \
    char* ab_ = lds + (b) * 32768 + wv * 1024;                              \
    _Pragma("unroll") for (int i = 0; i < 4; ++i) {                         \
      gld_lds16(Ab + (size_t)i * 32 * K + (kel), ab_ + i * 4096);           \
      gld_lds16(Bb + (size_t)i * 32 * K + (kel), ab_ + 16384 + i * 4096);   \
    } } while (0)

  const int NT = K >> 6;
  GSTAGE(0, 0);
  __syncthreads();

  for (int t = 0; t < NT; ++t) {
    const int cur = t & 1;
    if (t + 1 < NT) GSTAGE(cur ^ 1, (t + 1) << 6);
    const char* Ar = lds + cur * 32768;
    const char* Br = Ar + 16384;
#pragma unroll
    for (int kk = 0; kk < 2; ++kk) {
      bf16x8 af[4], bfv[4];
#pragma unroll
      for (int f = 0; f < 4; ++f) {
        af[f]  = *(const bf16x8*)(Ar + (wr * 64 + f * 16 + r) * 128 + ((kk * 64 + g * 16) ^ xr));
        bfv[f] = *(const bf16x8*)(Br + (wc * 64 + f * 16 + r) * 128 + ((kk * 64 + g * 16) ^ xr));
      }
#pragma unroll
      for (int fm = 0; fm < 4; ++fm)
#pragma unroll
        for (int fn = 0; fn < 4; ++fn)
          acc[fm][fn] = __builtin_amdgcn_mfma_f32_16x16x32_bf16(af[fm], bfv[fn], acc[fm][fn], 0, 0, 0);
    }
    __syncthreads();
  }
#undef GSTAGE

  float* epf = (float*)lds;   // [128][68 f32]
#pragma unroll
  for (int h = 0; h < 2; ++h) {
    __syncthreads();
    if (wc == h) {
#pragma unroll
      for (int fn = 0; fn < 4; ++fn) {
        const int n = n0 + h * 64 + fn * 16 + r;
        const float bvl = bias0[n];
#pragma unroll
        for (int fm = 0; fm < 4; ++fm)
#pragma unroll
          for (int j = 0; j < 4; ++j)
            epf[(wr * 64 + fm * 16 + 4 * g + j) * 68 + fn * 16 + r] = acc[fm][fn][j] + bvl;
      }
    }
    __syncthreads();
#pragma unroll
    for (int p = 0; p < 8; ++p) {
      const int row = p * 16 + (tid >> 4);
      const int seg = tid & 15;
      const f32x4 v4 = *(const f32x4*)(epf + row * 68 + seg * 4);
      *(f32x4*)(outf + (size_t)(m0 + row) * N + n0 + h * 64 + seg * 4) = v4;
    }
  }
}

// ---------------- flash attention (causal) — unchanged from R6 ----------------

__global__ __launch_bounds__(256) void attn_fwd(const unsigned short* __restrict__ Qm,
                                                const unsigned short* __restrict__ Km,
                                                const unsigned short* __restrict__ Vtm,
                                                unsigned short* __restrict__ Om) {
  __shared__ __align__(16) unsigned short Ks[2][4096];
  __shared__ __align__(16) unsigned short Vs[2][4096];

  const int tid = threadIdx.x, lane = tid & 63, wv = tid >> 6;
  const int g = lane >> 4, r = lane & 15;
  const int bh = blockIdx.x & 63;
  const int qp = 15 - (blockIdx.x >> 6);      // heavy blocks dispatch first

  const unsigned short* Qp = Qm + (size_t)bh * 131072;
  const unsigned short* Kp = Km + (size_t)bh * 131072;
  const unsigned short* Vp = Vtm + (size_t)bh * 131072;

  const int qb[2] = {qp * 128 + wv * 16, qp * 128 + 64 + wv * 16};

  bf16x8 qf[2][2];
#pragma unroll
  for (int mi = 0; mi < 2; ++mi)
#pragma unroll
    for (int h2 = 0; h2 < 2; ++h2)
      qf[mi][h2] = *(const bf16x8*)(Qp + (size_t)(qb[mi] + r) * 64 + h2 * 32 + g * 8);

  f32x4 oacc[2][4] = {};
  float m_[2] = {-__builtin_inff(), -__builtin_inff()};
  float l_[2] = {0.f, 0.f};

#define ASTAGE(buf, c) do {                                                      \
    const unsigned short* kg_ = Kp + (size_t)(c) * 4096;                         \
    const unsigned short* vg_ = Vp + (size_t)(c) * 4096;                         \
    const int o0_ = wv * 1024;                                                   \
    gld_lds16(kg_ + (o0_ >> 1) + lane * 8, (char*)Ks[buf] + o0_);                \
    gld_lds16(vg_ + (o0_ >> 1) + lane * 8, (char*)Vs[buf] + o0_);                \
    gld_lds16(kg_ + ((o0_ + 4096) >> 1) + lane * 8, (char*)Ks[buf] + o0_ + 4096);\
    gld_lds16(vg_ + ((o0_ + 4096) >> 1) + lane * 8, (char*)Vs[buf] + o0_ + 4096);\
  } while (0)

  const int nt = qp * 2 + 2;
  ASTAGE(0, 0);
  __syncthreads();

  for (int t = 0; t < nt; ++t) {
    const int cur = t & 1;
    if (t + 1 < nt) ASTAGE(cur ^ 1, t + 1);

    const char* KsT = (const char*)Ks[cur];
    const char* VsT = (const char*)Vs[cur];
    const int sw = (r & 7) << 4;
    bf16x8 kf[4][2], vf[4][2];
#pragma unroll
    for (int tt = 0; tt < 4; ++tt) {
      const int rowb = (tt * 16 + r) * 128;
#pragma unroll
      for (int kk = 0; kk < 2; ++kk) {
        const int cb = (kk * 64 + g * 16) ^ sw;
        kf[tt][kk] = *(const bf16x8*)(KsT + rowb + cb);
        vf[tt][kk] = *(const bf16x8*)(VsT + rowb + cb);
      }
    }

#pragma unroll
    for (int mi = 0; mi < 2; ++mi) {
      const int qbm = qb[mi];
      if (t * 64 > qbm + 15) continue;

      f32x4 sT[4];
      __builtin_amdgcn_s_setprio(1);
#pragma unroll
      for (int tt = 0; tt < 4; ++tt) {
        f32x4 a = {0.f, 0.f, 0.f, 0.f};
        a = __builtin_amdgcn_mfma_f32_16x16x32_bf16(kf[tt][0], qf[mi][0], a, 0, 0, 0);
        a = __builtin_amdgcn_mfma_f32_16x16x32_bf16(kf[tt][1], qf[mi][1], a, 0, 0, 0);
        sT[tt] = a;
      }
      __builtin_amdgcn_s_setprio(0);

      const int qg = qbm + r;
      if (t * 64 + 63 > qbm) {
#pragma unroll
        for (int tt = 0; tt < 4; ++tt)
#pragma unroll
          for (int j = 0; j < 4; ++j) {
            const int kv = t * 64 + tt * 16 + 4 * g + j;
            sT[tt][j] = (kv <= qg) ? sT[tt][j] : -__builtin_inff();
          }
      }

      float tm[4];
#pragma unroll
      for (int tt = 0; tt < 4; ++tt)
        tm[tt] = fmaxf(fmaxf(sT[tt][0], sT[tt][1]), fmaxf(sT[tt][2], sT[tt][3]));
      const float mx = fmaxf(fmaxf(tm[0], tm[1]), fmaxf(tm[2], tm[3]));

      float mcur = m_[mi];
      const bool norescale = __all(mx <= mcur + 4.0f);
      if (!norescale) {
        float rmx = mx;
        rmx = fmaxf(rmx, __shfl_xor(rmx, 16));
        rmx = fmaxf(rmx, __shfl_xor(rmx, 32));
        const float mnew = fmaxf(mcur, rmx);
        const float rs = fexp2(mcur - mnew);
        m_[mi] = mnew;
        mcur = mnew;
        l_[mi] *= rs;
        float rsb[4];
#pragma unroll
        for (int j = 0; j < 4; ++j) rsb[j] = __shfl(rs, 4 * g + j);
#pragma unroll
        for (int df = 0; df < 4; ++df)
#pragma unroll
          for (int j = 0; j < 4; ++j) oacc[mi][df][j] *= rsb[j];
      }

      float ts = 0.f;
#pragma unroll
      for (int tt = 0; tt < 4; ++tt)
#pragma unroll
        for (int j = 0; j < 4; ++j) {
          const float p = fexp2(sT[tt][j] - mcur);
          sT[tt][j] = p;
          ts += p;
        }
      l_[mi] += ts;

      union { uint32_t w[8]; bf16x8 v[2]; } pu;
#pragma unroll
      for (int tt = 0; tt < 4; ++tt) {
        asm("v_cvt_pk_bf16_f32 %0, %1, %2" : "=v"(pu.w[2 * tt])
            : "v"(sT[tt][0]), "v"(sT[tt][1]));
        asm("v_cvt_pk_bf16_f32 %0, %1, %2" : "=v"(pu.w[2 * tt + 1])
            : "v"(sT[tt][2]), "v"(sT[tt][3]));
      }

      __builtin_amdgcn_s_setprio(1);
#pragma unroll
      for (int kk = 0; kk < 2; ++kk)
#pragma unroll
        for (int df = 0; df < 4; ++df)
          oacc[mi][df] = __builtin_amdgcn_mfma_f32_16x16x32_bf16(pu.v[kk], vf[df][kk], oacc[mi][df], 0, 0, 0);
      __builtin_amdgcn_s_setprio(0);
    }
    __syncthreads();
  }
#undef ASTAGE

  const int b = bh >> 4, h = bh & 15;
#pragma unroll
  for (int mi = 0; mi < 2; ++mi) {
    float lt = l_[mi];
    lt += __shfl_xor(lt, 16);
    lt += __shfl_xor(lt, 32);
    float inv[4];
#pragma unroll
    for (int j = 0; j < 4; ++j) {
      const float lb = __shfl(lt, 4 * g + j);
      inv[j] = __builtin_amdgcn_rcpf(lb);
    }
#pragma unroll
    for (int df = 0; df < 4; ++df)
#pragma unroll
      for (int j = 0; j < 4; ++j) {
        const int trow = qb[mi] + 4 * g + j;
        const float ov = oacc[mi][df][j] * inv[j];
        const int col = (df * 16 + r) ^ ((trow & 7) << 3);
        Om[((size_t)(b * TSEQ + trow)) * 1024 + h * 64 + col] = f2bf(ov);
      }
  }
}

// ---------------- launch ----------------

extern "C" void kernel_launch(void* const* d_in, const int* in_sizes, int n_in,
                              void* d_out, int out_size, void* d_ws, size_t ws_size,
                              hipStream_t stream) {
  const float* x  = (const float*)d_in[0];
  const float* Wq = (const float*)d_in[1];
  const float* bq = (const float*)d_in[2];
  const float* Wk = (const float*)d_in[3];
  const float* bk = (const float*)d_in[4];
  const float* Wv = (const float*)d_in[5];
  const float* bv = (const float*)d_in[6];
  const float* Wo = (const float*)d_in[7];
  const float* bo = (const float*)d_in[8];
  float* out = (float*)d_out;

  unsigned short* xb  = (unsigned short*)d_ws;               // 8192*1024
  unsigned short* btq = xb + (size_t)8192 * 1024;            // 3072*1024
  unsigned short* wot = btq + (size_t)3072 * 1024;           // 1024*1024
  unsigned short* qb  = wot + (size_t)1024 * 1024;           // 64*2048*64
  unsigned short* kb  = qb + (size_t)64 * 2048 * 64;
  unsigned short* vtb = kb + (size_t)64 * 2048 * 64;

  cast_x_kernel<<<8192, 256, 0, stream>>>((const float4*)x, xb);
  repack_wqkv<<<dim3(16, 16, 3), 256, 0, stream>>>(Wq, Wk, Wv, btq);
  repack_wo<<<dim3(16, 16), 256, 0, stream>>>(Wo, wot);

  // QKV: [8192,1024] x [1024,3072] -> q/k/vT (attn layouts; q pre-scaled)
  gemm256<<<384, 512, 0, stream>>>(xb, btq, bq, bk, bv, qb, kb, vtb);
  // attention: 16 qp (heavy first) x 64 bh
  attn_fwd<<<1024, 256, 0, stream>>>(qb, kb, vtb, xb);
  // O-proj: [8192,1024] x [1024,1024] -> f32 out
  gemm_oproj<<<dim3(64, 8), 256, 0, stream>>>(xb, wot, bo, out, 1024, 1024);
}